// Round 3
// baseline (246.227 us; speedup 1.0000x reference)
//
#include <hip/hip_runtime.h>
#include <math.h>

// PCATemplateMap fused: x (64,2048,19,19) f32, templates (10,19,19) f32
// outputs: mask (64,1,19,19) then v (64,10), concatenated flat.
//
// Single fused kernel (+ tiny counter-init kernel):
//  phase 1: thread owns NCPT channels; Q[t] accumulated in registers with
//           template chunks read as wave-uniform global loads (no LDS in hot
//           loop); per-wave LDS transpose -> lane j owns S-slot j -> block
//           partial to ws.
//  phase 2 (last block of each batch, via atomic counter): reduce partials,
//           D = S2 - S1 S1^T / C, faithful fp32 LAPACK ssyevd
//           (ssytd2 LDS + ssteqr with lane-distributed registers/readlane +
//           argmax + single-column sormtr), then v and mask outputs.

#define NB   64
#define NC   2048
#define NHW  361
#define NTMP 10

struct f4 { float x, y, z, w; };
__device__ inline f4 load4u(const float* p){
    f4 r;
    __builtin_memcpy(&r, p, 16);
    return r;
}

__device__ inline float rl(float v, int i){
    return __int_as_float(__builtin_amdgcn_readlane(__float_as_int(v), i));
}

// =================== faithful fp32 LAPACK helpers =========================
__device__ inline float f_sign(float a, float b){
    return (b >= 0.f) ? fabsf(a) : -fabsf(a);     // Fortran SIGN(a,b)
}

__device__ inline float slapy2(float xx, float yy){
#pragma clang fp contract(off)
    float xa = fabsf(xx), ya = fabsf(yy);
    float w = fmaxf(xa, ya), z = fminf(xa, ya);
    if (z == 0.f) return w;
    float q = z / w;
    return w * sqrtf(1.f + q*q);
}

// LAPACK >= 3.10 slartg convention (c >= 0).
__device__ inline void slartg(float f, float g, float* cs, float* sn, float* rr){
#pragma clang fp contract(off)
    const float safmin = 0x1.0p-126f;
    const float safmax = 0x1.0p+126f;
    const float rtmin  = 0x1.0p-63f;
    const float rtmax  = 6.5211589e18f;  // sqrt(safmax/2)
    float f1 = fabsf(f), g1 = fabsf(g);
    if (g == 0.f){ *cs = 1.f; *sn = 0.f; *rr = f; }
    else if (f == 0.f){
        *cs = 0.f;
        *sn = (g >= 0.f) ? 1.f : -1.f;
        *rr = g1;
    } else {
        if (f1 > rtmin && f1 < rtmax && g1 > rtmin && g1 < rtmax){
            float d = sqrtf(f*f + g*g);
            *cs = f1 / d;
            *rr = (f >= 0.f) ? d : -d;
            *sn = g / (*rr);
        } else {
            float u = fminf(safmax, fmaxf(safmin, fmaxf(f1, g1)));
            float fs = f/u, gs = g/u;
            float d = sqrtf(fs*fs + gs*gs);
            *cs = fabsf(fs)/d;
            float r0 = (f >= 0.f) ? d : -d;
            *sn = gs / r0;
            *rr = r0 * u;
        }
    }
}

__device__ inline void slaev2(float a, float b, float c,
                              float* rt1, float* rt2, float* cs1, float* sn1){
#pragma clang fp contract(off)
    float sm = a + c;
    float df = a - c;
    float adf = fabsf(df);
    float tb = b + b;
    float ab = fabsf(tb);
    float acmx, acmn;
    if (fabsf(a) > fabsf(c)){ acmx = a; acmn = c; } else { acmx = c; acmn = a; }
    float rt;
    if (adf > ab){ float q = ab/adf; rt = adf*sqrtf(1.f + q*q); }
    else if (adf < ab){ float q = adf/ab; rt = ab*sqrtf(1.f + q*q); }
    else { rt = ab*sqrtf(2.f); }
    int sgn1;
    if (sm < 0.f){
        *rt1 = 0.5f*(sm - rt); sgn1 = -1;
        *rt2 = (acmx / *rt1)*acmn - (b / *rt1)*b;
    } else if (sm > 0.f){
        *rt1 = 0.5f*(sm + rt); sgn1 = 1;
        *rt2 = (acmx / *rt1)*acmn - (b / *rt1)*b;
    } else {
        *rt1 = 0.5f*rt; *rt2 = -0.5f*rt; sgn1 = 1;
    }
    float cs; int sgn2;
    if (df >= 0.f){ cs = df + rt; sgn2 = 1; }
    else { cs = df - rt; sgn2 = -1; }
    float acs = fabsf(cs);
    if (acs > ab){
        float ct = -tb/cs;
        *sn1 = 1.f/sqrtf(1.f + ct*ct);
        *cs1 = ct * (*sn1);
    } else {
        if (ab == 0.f){ *cs1 = 1.f; *sn1 = 0.f; }
        else {
            float tn = -cs/tb;
            *cs1 = 1.f/sqrtf(1.f + tn*tn);
            *sn1 = tn * (*cs1);
        }
    }
    if (sgn1 == sgn2){
        float tn = *cs1;
        *cs1 = -(*sn1);
        *sn1 = tn;
    }
}

#define A_(i,j) Aa[((j)-1)*10 + ((i)-1)]

// wave-cooperative ssyevd('V','L') n=10; lane 0..63 of one wave.
// ssytd2: LDS (lane-parallel O(n^2), scalar chain redundant on all lanes).
// ssteqr: dd/ee/wk and Z in lane-distributed REGISTERS (readlane gathers,
//         predicated writes) — identical arithmetic order to LAPACK.
// sormtr: single argmax column.
__device__ void eig10_wave(int lane, float* Aa, float* dd, float* ee,
                           float* tt, float* px, float* vout)
{
#pragma clang fp contract(off)
    const int n = 10;

    // ---------------- ssytd2 (lower) ----------------
    for (int i = 1; i <= n-1; i++){
        float alpha = A_(i+1, i);
        float ssq = 0.f;
        for (int k = i+2; k <= n; k++){ float v = A_(k,i); ssq += v*v; }
        float xnorm = sqrtf(ssq);
        float taui;
        if (xnorm == 0.f){
            taui = 0.f;
        } else {
            float beta = -f_sign(slapy2(alpha, xnorm), alpha);
            taui = (beta - alpha) / beta;
            float sc = 1.f / (alpha - beta);
            for (int k = i+2; k <= n; k++) A_(k,i) *= sc;   // all lanes same value
            alpha = beta;
        }
        ee[i] = alpha;
        if (taui != 0.f){
            A_(i+1, i) = 1.f;
            const int n2 = n - i;
            // parallel ssymv 'L': lane l2 computes px[l2]; contribution order
            // identical to LAPACK's interleaved j-loop.
            if (lane >= 1 && lane <= n2){
                const int l2 = lane;
                float p = 0.f;
                for (int j = 1; j <= l2-1; j++)
                    p = p + (taui * A_(i+j, i)) * A_(i+l2, i+j);
                p = p + (taui * A_(i+l2, i)) * A_(i+l2, i+l2);
                float temp2 = 0.f;
                for (int ii2 = l2+1; ii2 <= n2; ii2++)
                    temp2 = temp2 + A_(i+ii2, i+l2) * A_(i+ii2, i);
                p = p + taui * temp2;
                px[l2] = p;
            }
            // sdot (serial order, redundant on all lanes)
            float dot = 0.f;
            for (int j = 1; j <= n2; j++) dot = dot + px[j] * A_(i+j, i);
            float alpha2 = -0.5f * taui * dot;
            if (lane >= 1 && lane <= n2)
                px[lane] = px[lane] + alpha2 * A_(i+lane, i);
            // parallel ssyr2 'L': lane = column j
            if (lane >= 1 && lane <= n2){
                const int j = lane;
                float xj = A_(i+j, i);
                float yj = px[j];
                if (xj != 0.f || yj != 0.f){
                    float temp1 = -yj;
                    float temp2 = -xj;
                    for (int ii2 = j; ii2 <= n2; ii2++){
                        A_(i+ii2, i+j) = A_(i+ii2, i+j)
                                       + A_(i+ii2, i)*temp1 + px[ii2]*temp2;
                    }
                }
            }
            A_(i+1, i) = ee[i];
        }
        dd[i] = A_(i, i);
        tt[i] = taui;
    }
    dd[n] = A_(n, n);

    // ---------------- load distributed state ----------------
    float dd_r = (lane >= 1 && lane <= n)   ? dd[lane] : 0.f;
    float ee_r = (lane >= 1 && lane <= n-1) ? ee[lane] : 0.f;
    float wkc_r = 0.f, wks_r = 0.f;
    float z[10];           // lane j (1..10) holds Z column j, rows 0..9
    #pragma unroll
    for (int r = 0; r < 10; r++) z[r] = (lane == r+1) ? 1.f : 0.f;

    // rotation on columns (jj, jj+1): new[jj+1] = c*old[jj+1] - s*old[jj];
    //                                 new[jj]   = s*old[jj+1] + c*old[jj]
    auto ZROT = [&](int jj, float c, float s){
        #pragma unroll
        for (int r = 0; r < 10; r++){
            float a  = rl(z[r], jj+1);
            float bz = rl(z[r], jj);
            float na = c*a - s*bz;
            float nb = s*a + c*bz;
            z[r] = (lane == jj+1) ? na : ((lane == jj) ? nb : z[r]);
        }
    };

    // ---------------- ssteqr 'I' (register version) ----------------
    const float eps    = 0x1.0p-24f;
    const float eps2   = 0x1.0p-48f;
    const float safmin = 0x1.0p-126f;
    const int nmaxit = n * 30;
    int jtot = 0;
    int l1 = 1;

    while (true){
        if (l1 > n) break;
        if (l1 > 1){ if (lane == l1-1) ee_r = 0.f; }
        int m = n;
        if (l1 <= n-1){
            for (m = l1; m <= n-1; m++){
                float tst = fabsf(rl(ee_r, m));
                if (tst == 0.f) break;
                if (tst <= (sqrtf(fabsf(rl(dd_r, m))) * sqrtf(fabsf(rl(dd_r, m+1)))) * eps){
                    if (lane == m) ee_r = 0.f;
                    break;
                }
            }
        }
        int l = l1;
        int lsv = l;
        int lend = m;
        int lendsv = lend;
        l1 = m + 1;
        if (lend == l) continue;

        float anorm = 0.f;
        for (int k = l; k <= lend; k++)   anorm = fmaxf(anorm, fabsf(rl(dd_r, k)));
        for (int k = l; k <= lend-1; k++) anorm = fmaxf(anorm, fabsf(rl(ee_r, k)));
        if (anorm == 0.f) continue;

        if (fabsf(rl(dd_r, lend)) < fabsf(rl(dd_r, l))){
            lend = lsv;
            l = lendsv;
        }

        if (lend > l){
            // -------- QL --------
            while (true){
                int mq = lend;
                if (l != lend){
                    for (int t2 = l; t2 <= lend-1; t2++){
                        float ev = fabsf(rl(ee_r, t2));
                        if (ev*ev <= (eps2*fabsf(rl(dd_r, t2)))*fabsf(rl(dd_r, t2+1)) + safmin){
                            mq = t2; break;
                        }
                    }
                }
                if (mq < lend){ if (lane == mq) ee_r = 0.f; }
                float p = rl(dd_r, l);
                if (mq == l){
                    l = l + 1;
                    if (l <= lend) continue;
                    break;
                }
                if (mq == l+1){
                    float rt1, rt2, cc, ss;
                    slaev2(rl(dd_r, l), rl(ee_r, l), rl(dd_r, l+1), &rt1, &rt2, &cc, &ss);
                    ZROT(l, cc, ss);
                    if (lane == l)   dd_r = rt1;
                    if (lane == l+1) dd_r = rt2;
                    if (lane == l)   ee_r = 0.f;
                    l += 2;
                    if (l <= lend) continue;
                    break;
                }
                if (jtot == nmaxit) break;
                jtot++;
                float g = (rl(dd_r, l+1) - p) / (2.f * rl(ee_r, l));
                float r0 = slapy2(g, 1.f);
                g = rl(dd_r, mq) - p + (rl(ee_r, l) / (g + f_sign(r0, g)));
                float ss = 1.f, cc = 1.f;
                p = 0.f;
                for (int i2 = mq-1; i2 >= l; i2--){
                    float e2 = rl(ee_r, i2);
                    float ff = ss * e2;
                    float bb = cc * e2;
                    float rr;
                    slartg(g, ff, &cc, &ss, &rr);
                    if (i2 != mq-1){ if (lane == i2+1) ee_r = rr; }
                    g = rl(dd_r, i2+1) - p;
                    rr = (rl(dd_r, i2) - g)*ss + 2.f*cc*bb;
                    p = ss*rr;
                    if (lane == i2+1) dd_r = g + p;
                    g = cc*rr - bb;
                    if (lane == i2){ wkc_r = cc; wks_r = -ss; }
                }
                for (int jj = mq-1; jj >= l; jj--){
                    float ct = rl(wkc_r, jj), st = rl(wks_r, jj);
                    if (ct != 1.f || st != 0.f) ZROT(jj, ct, st);
                }
                if (lane == l) dd_r = dd_r - p;
                if (lane == l) ee_r = g;
            }
        } else {
            // -------- QR --------
            while (true){
                int mq = lend;
                if (l != lend){
                    for (int t2 = l; t2 >= lend+1; t2--){
                        float ev = fabsf(rl(ee_r, t2-1));
                        if (ev*ev <= (eps2*fabsf(rl(dd_r, t2)))*fabsf(rl(dd_r, t2-1)) + safmin){
                            mq = t2; break;
                        }
                    }
                }
                if (mq > lend){ if (lane == mq-1) ee_r = 0.f; }
                float p = rl(dd_r, l);
                if (mq == l){
                    l = l - 1;
                    if (l >= lend) continue;
                    break;
                }
                if (mq == l-1){
                    float rt1, rt2, cc, ss;
                    slaev2(rl(dd_r, l-1), rl(ee_r, l-1), rl(dd_r, l), &rt1, &rt2, &cc, &ss);
                    ZROT(l-1, cc, ss);
                    if (lane == l-1) dd_r = rt1;
                    if (lane == l)   dd_r = rt2;
                    if (lane == l-1) ee_r = 0.f;
                    l -= 2;
                    if (l >= lend) continue;
                    break;
                }
                if (jtot == nmaxit) break;
                jtot++;
                float g = (rl(dd_r, l-1) - p) / (2.f * rl(ee_r, l-1));
                float r0 = slapy2(g, 1.f);
                g = rl(dd_r, mq) - p + (rl(ee_r, l-1) / (g + f_sign(r0, g)));
                float ss = 1.f, cc = 1.f;
                p = 0.f;
                for (int i2 = mq; i2 <= l-1; i2++){
                    float e2 = rl(ee_r, i2);
                    float ff = ss * e2;
                    float bb = cc * e2;
                    float rr;
                    slartg(g, ff, &cc, &ss, &rr);
                    if (i2 != mq){ if (lane == i2-1) ee_r = rr; }
                    g = rl(dd_r, i2) - p;
                    rr = (rl(dd_r, i2+1) - g)*ss + 2.f*cc*bb;
                    p = ss*rr;
                    if (lane == i2) dd_r = g + p;
                    g = cc*rr - bb;
                    if (lane == i2){ wkc_r = cc; wks_r = ss; }
                }
                for (int jj = mq; jj <= l-1; jj++){
                    float ct = rl(wkc_r, jj), st = rl(wks_r, jj);
                    if (ct != 1.f || st != 0.f) ZROT(jj, ct, st);
                }
                if (lane == l)   dd_r = dd_r - p;
                if (lane == l-1) ee_r = g;
            }
        }
        if (jtot < nmaxit) continue;
        break;
    }

    // ---------------- argmax (ascending sort's last == max) ----------------
    int kmax = 1;
    float pmax = rl(dd_r, 1);
    for (int j = 2; j <= n; j++){
        float dj = rl(dd_r, j);
        if (dj > pmax){ pmax = dj; kmax = j; }
    }

    // extract column kmax -> lane-distributed vcol (lane r+1 holds row r+1)
    float vc = 0.f;
    #pragma unroll
    for (int r = 0; r < 10; r++){
        float s = rl(z[r], kmax);
        vc = (lane == r+1) ? s : vc;
    }

    // ---------------- sormtr 'L','L','N' on the single column ------------
    for (int i = n-1; i >= 1; i--){
        float taui = tt[i];
        if (taui != 0.f){
            float s1 = rl(vc, i+1);
            for (int r2 = i+2; r2 <= n; r2++) s1 = s1 + A_(r2, i) * rl(vc, r2);
            s1 = taui * s1;
            if (lane == i+1) vc = vc - s1;
            if (lane >= i+2 && lane <= n) vc = vc - A_(lane, i) * s1;
        }
    }
    if (lane >= 1 && lane <= n) vout[lane-1] = vc;
}

// ======================= init: zero per-batch counters ====================
__global__ void k_init(unsigned* __restrict__ cnt){
    if (threadIdx.x < NB) cnt[threadIdx.x] = 0u;
}

// ======================= fused kernel =====================================
template<int CBLK>
__global__ __launch_bounds__(256) void fused(
        const float* __restrict__ x, const float* __restrict__ tmpl,
        float* __restrict__ out, float* __restrict__ partial,
        unsigned* __restrict__ cnt)
{
    constexpr int NCPT = NC / (CBLK * 256);           // channels per thread
    constexpr int U    = (NCPT == 1) ? 15 : ((NCPT == 2) ? 6 : 3);

    __shared__ float QL[4][64][13];
    __shared__ float red[4][66];
    __shared__ float SS[66];
    __shared__ float Aa[100];
    __shared__ float dd[12], ee[12], tt[12], px[12], vout[12];
    __shared__ int flag;

    const int tid  = threadIdx.x;
    const int lane = tid & 63;
    const int wid  = tid >> 6;
    const int b    = blockIdx.x / CBLK;
    const int cb   = blockIdx.x % CBLK;

    // ---------------- phase 1: per-thread Q over NCPT channels -----------
    const float* xr[NCPT];
    #pragma unroll
    for (int s = 0; s < NCPT; s++)
        xr[s] = x + ((size_t)b*NC + (size_t)cb*(256*NCPT) + s*256 + tid)*NHW;

    float acc[NCPT][NTMP];
    #pragma unroll
    for (int s = 0; s < NCPT; s++)
        #pragma unroll
        for (int t = 0; t < NTMP; t++) acc[s][t] = 0.f;

    for (int c0 = 0; c0 < 90; c0 += U){
        #pragma unroll
        for (int u = 0; u < U; u++){
            const int i0 = (c0 + u)*4;
            f4 xv[NCPT];
            #pragma unroll
            for (int s = 0; s < NCPT; s++) xv[s] = load4u(xr[s] + i0);
            #pragma unroll
            for (int t = 0; t < NTMP; t++){
                const f4 tv = load4u(tmpl + t*NHW + i0);   // wave-uniform
                #pragma unroll
                for (int s = 0; s < NCPT; s++)
                    acc[s][t] += xv[s].x*tv.x + xv[s].y*tv.y
                               + xv[s].z*tv.z + xv[s].w*tv.w;
            }
        }
    }
    #pragma unroll
    for (int s = 0; s < NCPT; s++){
        const float xt = xr[s][360];
        #pragma unroll
        for (int t = 0; t < NTMP; t++) acc[s][t] += xt * tmpl[t*NHW + 360];
    }

    // ---------------- per-wave S1/S2 via LDS transpose --------------------
    // lane < 55: S2 pair k=lane -> (tA,uA); lanes 55..63: S1 t=lane-55;
    // lane 54 (pair 9,9) also accumulates S1 t=9.
    int tA, uA;
    {
        if (lane < 55){
            int k = lane, t = 0;
            while (k >= 10 - t){ k -= 10 - t; t++; }
            tA = t; uA = t + k;
        } else { tA = lane - 55; uA = tA; }
    }
    float sv = 0.f, s1v = 0.f;
    #pragma unroll
    for (int s = 0; s < NCPT; s++){
        #pragma unroll
        for (int t = 0; t < NTMP; t++) QL[wid][lane][t] = acc[s][t];
        // same wave: DS ops in order; compiler inserts lgkmcnt for the reads
        #pragma unroll 8
        for (int c = 0; c < 64; c++){
            float qt = QL[wid][c][tA];
            float qu = QL[wid][c][uA];
            sv  += qt*qu;
            s1v += qt;
        }
    }
    if (lane < 55) red[wid][10 + lane] = sv;
    else           red[wid][lane - 55] = s1v;
    if (lane == 54) red[wid][9] = s1v;
    __syncthreads();

    if (tid < 65){
        float v = red[0][tid] + red[1][tid] + red[2][tid] + red[3][tid];
        partial[(size_t)blockIdx.x*65 + tid] = v;
    }
    __threadfence();
    __syncthreads();
    if (tid == 0){
        unsigned old = atomicAdd(&cnt[b], 1u);
        flag = (old == (unsigned)(CBLK - 1)) ? 1 : 0;
    }
    __syncthreads();
    if (!flag) return;
    __threadfence();

    // ---------------- phase 2: last block of batch b ----------------------
    if (tid < 65){
        float v = 0.f;
        for (int p2 = 0; p2 < CBLK; p2++)
            v += partial[((size_t)b*CBLK + p2)*65 + tid];
        SS[tid] = v;
    }
    __syncthreads();

    // D[t][s] = S2 - S1 S1^T / C (exactly symmetric), col-major in Aa
    if (tid < 100){
        int t = tid % 10, s2 = tid / 10;
        int lo = t < s2 ? t : s2, hi = t < s2 ? s2 : t;
        int pk = 10*lo - (lo*(lo-1))/2 + (hi - lo);
        Aa[s2*10 + t] = SS[10 + pk] - SS[t]*SS[s2]*(1.0f/2048.0f);
    }
    __syncthreads();

    if (tid < 64) eig10_wave(tid, Aa, dd, ee, tt, px, vout);
    __syncthreads();

    if (tid >= 1 && tid <= NTMP)
        out[(size_t)NB*NHW + (size_t)b*NTMP + (tid-1)] = vout[tid-1];

    for (int i = tid; i < NHW; i += 256){
        float m2 = 0.f;
        #pragma unroll
        for (int t = 0; t < NTMP; t++) m2 += vout[t] * tmpl[t*NHW + i];
        out[(size_t)b*NHW + i] = m2;
    }
}

// ============================== launcher ==================================
extern "C" void kernel_launch(void* const* d_in, const int* in_sizes, int n_in,
                              void* d_out, int out_size, void* d_ws, size_t ws_size,
                              hipStream_t stream)
{
    const float* x    = (const float*)d_in[0];
    const float* tmpl = (const float*)d_in[1];
    float* out = (float*)d_out;
    unsigned* cnt  = (unsigned*)d_ws;
    float* partial = (float*)((char*)d_ws + 256);

    k_init<<<dim3(1), dim3(64), 0, stream>>>(cnt);

    const size_t need8 = 256 + (size_t)NB*8*65*sizeof(float);
    const size_t need4 = 256 + (size_t)NB*4*65*sizeof(float);
    if (ws_size >= need8){
        fused<8><<<dim3(NB*8), dim3(256), 0, stream>>>(x, tmpl, out, partial, cnt);
    } else if (ws_size >= need4){
        fused<4><<<dim3(NB*4), dim3(256), 0, stream>>>(x, tmpl, out, partial, cnt);
    } else {
        fused<2><<<dim3(NB*2), dim3(256), 0, stream>>>(x, tmpl, out, partial, cnt);
    }
}